// Round 2
// baseline (178.792 us; speedup 1.0000x reference)
//
#include <hip/hip_runtime.h>

// RoutingBlock: per-batch argmax over 4 routing logits selects a 128-channel
// slice of the 512-channel input. Output (64,32,32,128) fp32.
//
// Layout constants:
//   B=64, H=32, W=32, C=512, ROUTES=4, RW=128
//   out float4 total      = 64*32*32*128/4 = 2,097,152
//   out float4 per batch  = 32768
//   2 float4 per thread, 256 threads/block -> 512 f4/block -> 64 blocks/batch
//   => b = blockIdx.x >> 6 is PURELY scalar: the rx loads + argmax compile to
//      s_load_dwordx4 + s_cmp/s_cselect (no LDS, no barrier, free broadcast).

__global__ __launch_bounds__(256) void routing_gather_kernel(
    const float4* __restrict__ in,      // B*H*W*512 floats as float4
    const float*  __restrict__ rx,      // B*4 routing logits
    float4*       __restrict__ out)     // B*H*W*128 floats as float4
{
    const int blk = blockIdx.x;
    const int b   = blk >> 6;           // batch index (scalar-uniform)

    // Scalar-path 4-way argmax; strict > keeps first-occurrence semantics
    // matching jnp.argmax.
    const float* r = rx + (b << 2);
    float v0 = r[0], v1 = r[1], v2 = r[2], v3 = r[3];
    int route = 0; float mv = v0;
    if (v1 > mv) { mv = v1; route = 1; }
    if (v2 > mv) { mv = v2; route = 2; }
    if (v3 > mv) { mv = v3; route = 3; }

    const int base = blk << 9;          // 512 out-f4 per block

    #pragma unroll
    for (int j = 0; j < 2; ++j) {
        const int i      = base + (j << 8) + threadIdx.x;  // out f4 index
        const int within = i & 32767;    // out f4 within batch
        const int s      = within >> 5;  // pixel within batch (0..1023)
        const int c4     = within & 31;  // f4 within 128-ch slice

        // input f4 index: ((b*1024 + s) * 128) + route*32 + c4
        const int in_idx = (((b << 10) + s) << 7) + (route << 5) + c4;
        out[i] = in[in_idx];
    }
}

extern "C" void kernel_launch(void* const* d_in, const int* in_sizes, int n_in,
                              void* d_out, int out_size, void* d_ws, size_t ws_size,
                              hipStream_t stream) {
    const float4* in  = (const float4*)d_in[0];   // inputs  (64,32,32,512) fp32
    const float*  rx  = (const float*)d_in[1];    // routing_x (64,4) fp32
    float4*       out = (float4*)d_out;           // (64,32,32,128) fp32

    routing_gather_kernel<<<4096, 256, 0, stream>>>(in, rx, out);
}